// Round 15
// baseline (218.884 us; speedup 1.0000x reference)
//
#include <hip/hip_runtime.h>
#include <cstdint>

#define BATCH 8
#define NPART 2048
#define DDIM 8
#define NN (NPART * NPART) /* 4194304 ordered pairs per batch */

#define MJCHUNK 128   // median j-tile: 4.6 KB stage + 32 KB hist -> 4 blocks/CU

constexpr float LR = 0.1f;
constexpr float ALPHA = 0.9f;
constexpr float EPS = 1e-8f;
constexpr float INV_N = 1.0f / (float)NPART;
constexpr float LOG2E = 1.44269504088896340736f;

typedef float v2f __attribute__((ext_vector_type(2)));
typedef float v4f __attribute__((ext_vector_type(4)));

// ---------------------------------------------------------------------------
// init: zero radix histograms + select state (RMSprop s is never pre-zeroed:
// the first svgd step computes s = (1-a)*phi^2 directly, not reading s).
// ---------------------------------------------------------------------------
__global__ __launch_bounds__(256) void init_ws_k(unsigned* __restrict__ hist,
                                                 unsigned* __restrict__ prefix,
                                                 unsigned* __restrict__ rank) {
    const int tid = blockIdx.x * 256 + threadIdx.x;
    if (tid < BATCH * 2 * 256) hist[tid] = 0u;
    if (tid < BATCH * 2) {
        prefix[tid] = 0u;
        rank[tid] = (unsigned)(NN / 2) + (unsigned)(tid & 1); // 2097152 / 2097153
    }
}

// ---------------------------------------------------------------------------
// SYMMETRIC radix-select histogram pass (round-11 proven, unchanged).
// ---------------------------------------------------------------------------
__global__ __launch_bounds__(256) void median_hist_k(const float* __restrict__ x,
                                                     unsigned* __restrict__ hist,
                                                     const unsigned* __restrict__ prefix,
                                                     int shift) {
    __shared__ __align__(16) v4f xs0[MJCHUNK]; // xj dims 0-3
    __shared__ __align__(16) v4f xs1[MJCHUNK]; // xj dims 4-7
    __shared__ float rs[MJCHUNK];              // |xj|^2
    __shared__ unsigned lh[256 * 32];          // 32 KB slot-privatized bins

    const int b = blockIdx.x;
    const int tid = threadIdx.x;
    const int lane = tid & 63;   // j-lane
    const int slot = tid & 31;
    const int trow = tid >> 6;   // 0..3
    const float* xb = x + (size_t)b * NPART * DDIM;

    const unsigned p0 = prefix[2 * b + 0];
    const unsigned p1 = prefix[2 * b + 1];
    const bool same = (p0 == p1);
    const unsigned mask = (shift == 24) ? 0u : (0xFFFFFFFFu << (shift + 8));

    const int nsel = same ? 1 : 2;
    for (int sel = 0; sel < nsel; ++sel) {
        const unsigned pref = sel ? p1 : p0;
        __syncthreads();
        for (int t = tid; t < 256 * 32; t += 256) lh[t] = 0u;

        for (int sp = 0; sp < 2; ++sp) {
            const int strip = sp ? (255 - (int)blockIdx.y) : (int)blockIdx.y;
            const int ibase = strip * 8 + trow * 2;
            v2f xi[2][4];
            float q[2];
#pragma unroll
            for (int rr = 0; rr < 2; ++rr) {
                const v4f t0 = ((const v4f*)(xb + (size_t)(ibase + rr) * DDIM))[0];
                const v4f t1 = ((const v4f*)(xb + (size_t)(ibase + rr) * DDIM))[1];
                xi[rr][0] = t0.xy; xi[rr][1] = t0.zw;
                xi[rr][2] = t1.xy; xi[rr][3] = t1.zw;
                q[rr] = t0.x * t0.x + t0.y * t0.y + t0.z * t0.z + t0.w * t0.w
                      + t1.x * t1.x + t1.y * t1.y + t1.z * t1.z + t1.w * t1.w;
            }
            const int c0 = (strip >> 4) * MJCHUNK; // first chunk touching strip
            for (int cbase = c0; cbase < NPART; cbase += MJCHUNK) {
                __syncthreads();
                for (int t = tid; t < MJCHUNK; t += 256) {
                    const v4f u0 = ((const v4f*)(xb + (size_t)(cbase + t) * DDIM))[0];
                    const v4f u1 = ((const v4f*)(xb + (size_t)(cbase + t) * DDIM))[1];
                    xs0[t] = u0;
                    xs1[t] = u1;
                    rs[t] = u0.x * u0.x + u0.y * u0.y + u0.z * u0.z + u0.w * u0.w
                          + u1.x * u1.x + u1.y * u1.y + u1.z * u1.z + u1.w * u1.w;
                }
                __syncthreads();
#pragma unroll
                for (int j = lane; j < MJCHUNK; j += 64) {
                    const int jg = cbase + j;
                    const v4f A = xs0[j];
                    const v4f B = xs1[j];
                    const float r = rs[j];
                    const v2f A0 = A.xy, A1 = A.zw, B0 = B.xy, B1 = B.zw;
#pragma unroll
                    for (int rr = 0; rr < 2; ++rr) {
                        v2f p = A0 * xi[rr][0];
                        p += A1 * xi[rr][1];
                        p += B0 * xi[rr][2];
                        p += B1 * xi[rr][3];
                        const float sq = fmaxf(fmaf(-2.0f, p.x + p.y, q[rr] + r), 0.0f);
                        const unsigned u = __float_as_uint(sq);
                        if (jg > ibase + rr && (u & mask) == pref)
                            atomicAdd(&lh[((u >> shift) & 255u) * 32 + slot], 2u);
                    }
                }
            }
        }
        __syncthreads();
        unsigned tot = 0;
#pragma unroll
        for (int sct = 0; sct < 32; ++sct) tot += lh[tid * 32 + ((sct + tid) & 31)];
        if (tot) {
            atomicAdd(&hist[b * 512 + sel * 256 + tid], tot);
            if (same) atomicAdd(&hist[b * 512 + 256 + tid], tot);
        }
    }
}

// ---------------------------------------------------------------------------
// scan (round-11 proven, unchanged): diagonal zeros added analytically.
// Final round (shift==8): hpar = { -log2e/h, 2/h }.
// ---------------------------------------------------------------------------
__global__ void median_scan_k(unsigned* __restrict__ hist,
                              unsigned* __restrict__ prefix,
                              unsigned* __restrict__ rank,
                              int shift,
                              float* __restrict__ hpar) {
    __shared__ unsigned selv[16];
    const int t = threadIdx.x;
    if (t < 16) {
        const unsigned r = rank[t];
        const unsigned pref = prefix[t];
        const unsigned* hb = hist + t * 256;
        unsigned cum = 0;
        int bin = 0;
        for (; bin < 256; ++bin) {
            unsigned c = hb[bin];
            if (bin == 0 && pref == 0u) c += (unsigned)NPART; // diagonal zeros
            if (cum + c >= r) break;
            cum += c;
        }
        if (bin > 255) bin = 255;
        const unsigned np = pref | ((unsigned)bin << shift);
        prefix[t] = np;
        rank[t] = r - cum;
        selv[t] = np;
    }
    __syncthreads();
    for (int q = t; q < 16 * 256; q += 64) hist[q] = 0u;
    if (shift == 8 && t < BATCH) {
        const float v1 = __uint_as_float(selv[2 * t + 0]);
        const float v2 = __uint_as_float(selv[2 * t + 1]);
        const float med = 0.5f * (sqrtf(v1) + sqrtf(v2));
        const float h = (med * med) / logf((float)NPART);
        hpar[2 * t + 0] = -LOG2E / h;
        hpar[2 * t + 1] = 2.0f / h;
    }
}

// ---------------------------------------------------------------------------
// rs seed for the first svgd step: rs[row] = nih2_b * |x0_row|^2.
// Must run AFTER the median (needs hpar). 16384 rows.
// ---------------------------------------------------------------------------
__global__ __launch_bounds__(256) void rs0_k(const float* __restrict__ x,
                                             const float* __restrict__ hpar,
                                             float* __restrict__ rs) {
    const int row = blockIdx.x * 256 + threadIdx.x;
    if (row < BATCH * NPART) {
        const int b = row >> 11;
        const float nih2 = hpar[2 * b + 0];
        const v4f t0 = ((const v4f*)(x + (size_t)row * DDIM))[0];
        const v4f t1 = ((const v4f*)(x + (size_t)row * DDIM))[1];
        rs[row] = nih2 * (t0.x * t0.x + t0.y * t0.y + t0.z * t0.z + t0.w * t0.w
                        + t1.x * t1.x + t1.y * t1.y + t1.z * t1.z + t1.w * t1.w);
    }
}

// ---------------------------------------------------------------------------
// one SVGD + RMSprop step, dot-expansion in exp2 domain — barrier-free main
// loop, 8 i-rows per thread (halves VMEM/L1 bytes per pair vs 4 rows):
//   K = exp2(cdot2*<xi,xj> + q + rs_j), q = nih2*|xi|^2
//   S0 = sum_j K;  V_d = sum_j K*xj_d;  U_d = S0*xi_d - V_d
//   phi = (1/N) * ( S0*(obs_d - xi_d) + (1 + 2/h)*U_d )
// block 256 = 64 j-lanes x 4 trows x 8 rows = 32 rows/block; grid (BATCH, 64).
// Per-pair fp32 ops, j-partition (64 lanes), and reduce order are identical
// to the round-13 kernel -> phi bitwise-identical.
// Epilogue writes rs_out from the new x (8-lane shfl row reduction).
// first=1: RMSprop state treated as zero (not read).
// ---------------------------------------------------------------------------
__global__ __launch_bounds__(256, 2) void svgd_step_k(const float* __restrict__ x_in,
                                                      float* __restrict__ x_out,
                                                      float* __restrict__ s,
                                                      const float* __restrict__ hpar,
                                                      const float* __restrict__ obs,
                                                      const float* __restrict__ rs_in,
                                                      float* __restrict__ rs_out,
                                                      int first) {
    __shared__ float part[32][8][9]; // 9.2 KB partial combine

    const int b = blockIdx.x;
    const int tid = threadIdx.x;
    const int lane = tid & 63;  // j-lane
    const int trow = tid >> 6;  // 0..3
    const float* xb = x_in + (size_t)b * NPART * DDIM;
    const float* rb = rs_in + (size_t)b * NPART;

    const float nih2 = hpar[2 * b + 0];  // -log2e/h
    const float c2 = hpar[2 * b + 1];    //  2/h
    const float cdot2 = -2.0f * nih2;

    const int ibase = blockIdx.y * 32 + trow * 8;
    v2f xi[8][4];
    float q[8];
#pragma unroll
    for (int rr = 0; rr < 8; ++rr) {
        const v4f t0 = ((const v4f*)(xb + (size_t)(ibase + rr) * DDIM))[0];
        const v4f t1 = ((const v4f*)(xb + (size_t)(ibase + rr) * DDIM))[1];
        xi[rr][0] = t0.xy; xi[rr][1] = t0.zw;
        xi[rr][2] = t1.xy; xi[rr][3] = t1.zw;
        q[rr] = nih2 * (t0.x * t0.x + t0.y * t0.y + t0.z * t0.z + t0.w * t0.w
                      + t1.x * t1.x + t1.y * t1.y + t1.z * t1.z + t1.w * t1.w);
    }

    float S0[8] = {0, 0, 0, 0, 0, 0, 0, 0};
    v2f V[8][4];
#pragma unroll
    for (int rr = 0; rr < 8; ++rr)
#pragma unroll
        for (int k = 0; k < 4; ++k) V[rr][k] = (v2f){0, 0};

#pragma unroll 2
    for (int j = lane; j < NPART; j += 64) {
        const v4f A = ((const v4f*)(xb + (size_t)j * DDIM))[0];
        const v4f B = ((const v4f*)(xb + (size_t)j * DDIM))[1];
        const float r = rb[j];
        const v2f A0 = A.xy, A1 = A.zw, B0 = B.xy, B1 = B.zw;
#pragma unroll
        for (int rr = 0; rr < 8; ++rr) {
            v2f p = A0 * xi[rr][0];
            p += A1 * xi[rr][1];
            p += B0 * xi[rr][2];
            p += B1 * xi[rr][3];
            const float K = __builtin_amdgcn_exp2f(fmaf(cdot2, p.x + p.y, q[rr] + r));
            S0[rr] += K;
            const v2f K2 = {K, K};
            V[rr][0] += A0 * K2;
            V[rr][1] += A1 * K2;
            V[rr][2] += B0 * K2;
            V[rr][3] += B1 * K2;
        }
    }

    // in-register lane pre-reduce (64 -> 8 partial lanes), then LDS combine
#pragma unroll
    for (int rr = 0; rr < 8; ++rr) {
        float t0 = S0[rr];
        float t1 = V[rr][0].x, t2 = V[rr][0].y;
        float t3 = V[rr][1].x, t4 = V[rr][1].y;
        float t5 = V[rr][2].x, t6 = V[rr][2].y;
        float t7 = V[rr][3].x, t8 = V[rr][3].y;
        t0 += __shfl_xor(t0, 32); t0 += __shfl_xor(t0, 16); t0 += __shfl_xor(t0, 8);
        t1 += __shfl_xor(t1, 32); t1 += __shfl_xor(t1, 16); t1 += __shfl_xor(t1, 8);
        t2 += __shfl_xor(t2, 32); t2 += __shfl_xor(t2, 16); t2 += __shfl_xor(t2, 8);
        t3 += __shfl_xor(t3, 32); t3 += __shfl_xor(t3, 16); t3 += __shfl_xor(t3, 8);
        t4 += __shfl_xor(t4, 32); t4 += __shfl_xor(t4, 16); t4 += __shfl_xor(t4, 8);
        t5 += __shfl_xor(t5, 32); t5 += __shfl_xor(t5, 16); t5 += __shfl_xor(t5, 8);
        t6 += __shfl_xor(t6, 32); t6 += __shfl_xor(t6, 16); t6 += __shfl_xor(t6, 8);
        t7 += __shfl_xor(t7, 32); t7 += __shfl_xor(t7, 16); t7 += __shfl_xor(t7, 8);
        t8 += __shfl_xor(t8, 32); t8 += __shfl_xor(t8, 16); t8 += __shfl_xor(t8, 8);
        if (lane < 8) {
            const int row = trow * 8 + rr;
            part[row][lane][0] = t0;
            part[row][lane][1] = t1;
            part[row][lane][2] = t2;
            part[row][lane][3] = t3;
            part[row][lane][4] = t4;
            part[row][lane][5] = t5;
            part[row][lane][6] = t6;
            part[row][lane][7] = t7;
            part[row][lane][8] = t8;
        }
    }
    __syncthreads();

    // phase 2: 256 threads = 32 rows x 8 dims; reduce 8 lane-partials
    {
        const int d2i = tid & 7;
        const int r2 = tid >> 3;
        const int i2 = blockIdx.y * 32 + r2;
        float S0t = 0.0f, Vt = 0.0f;
#pragma unroll
        for (int l = 0; l < 8; ++l) {
            S0t += part[r2][l][0];
            Vt += part[r2][l][1 + d2i];
        }
        const size_t idx = ((size_t)b * NPART + i2) * DDIM + d2i;
        const float xid = x_in[idx];
        const float obsd = obs[b * DDIM + d2i];
        const float U = fmaf(S0t, xid, -Vt);       // sum_j K*(xi - xj)
        const float T = fmaf(S0t, obsd - xid, U);  // sum_j K*(obs - xj)
        const float phi = INV_N * fmaf(c2, U, T);
        float sv;
        if (first) {
            sv = (1.0f - ALPHA) * phi * phi;
        } else {
            sv = ALPHA * s[idx] + (1.0f - ALPHA) * phi * phi;
        }
        s[idx] = sv;
        const float xn = xid + LR * phi / (sqrtf(sv) + EPS);
        x_out[idx] = xn;
        // rs for the NEXT step: row-sum of xn^2 over the 8 dims (8-lane group)
        float sq = xn * xn;
        sq += __shfl_xor(sq, 1);
        sq += __shfl_xor(sq, 2);
        sq += __shfl_xor(sq, 4);
        if (d2i == 0) rs_out[(size_t)b * NPART + i2] = nih2 * sq;
    }
}

// ---------------------------------------------------------------------------
extern "C" void kernel_launch(void* const* d_in, const int* in_sizes, int n_in,
                              void* d_out, int out_size, void* d_ws, size_t ws_size,
                              hipStream_t stream) {
    const float* x0 = (const float*)d_in[0];   // [8,2048,8]
    const float* obs = (const float*)d_in[1];  // [8,8]
    float* out = (float*)d_out;                // [8,2048,8]

    // workspace layout (~1.2 MB)
    float* xa = (float*)d_ws;                          // ping-pong x
    float* s = xa + BATCH * NPART * DDIM;              // RMSprop state
    unsigned* hist = (unsigned*)(s + BATCH * NPART * DDIM);
    unsigned* prefix = hist + BATCH * 2 * 256;
    unsigned* rank = prefix + BATCH * 2;
    float* hpar = (float*)(rank + BATCH * 2);
    float* rsA = hpar + BATCH * 2;                     // 64 KB
    float* rsB = rsA + BATCH * NPART;                  // 64 KB

    init_ws_k<<<16, 256, 0, stream>>>(hist, prefix, rank);

    // median via 3-round SYMMETRIC radix select on float bit patterns
    for (int r = 0; r < 3; ++r) {
        const int shift = 24 - 8 * r;
        median_hist_k<<<dim3(BATCH, 128), 256, 0, stream>>>(x0, hist, prefix, shift);
        median_scan_k<<<1, 64, 0, stream>>>(hist, prefix, rank, shift, hpar);
    }

    // seed rs from x0 (needs hpar -> after median)
    rs0_k<<<64, 256, 0, stream>>>(x0, hpar, rsA);

    // 5 SVGD iterations, ping-ponging x between d_out and ws and rs A<->B
    svgd_step_k<<<dim3(BATCH, 64), 256, 0, stream>>>(x0, out, s, hpar, obs, rsA, rsB, 1);
    svgd_step_k<<<dim3(BATCH, 64), 256, 0, stream>>>(out, xa, s, hpar, obs, rsB, rsA, 0);
    svgd_step_k<<<dim3(BATCH, 64), 256, 0, stream>>>(xa, out, s, hpar, obs, rsA, rsB, 0);
    svgd_step_k<<<dim3(BATCH, 64), 256, 0, stream>>>(out, xa, s, hpar, obs, rsB, rsA, 0);
    svgd_step_k<<<dim3(BATCH, 64), 256, 0, stream>>>(xa, out, s, hpar, obs, rsA, rsB, 0);
}

// Round 16
// 215.526 us; speedup vs baseline: 1.0156x; 1.0156x over previous
//
#include <hip/hip_runtime.h>
#include <cstdint>

#define BATCH 8
#define NPART 2048
#define DDIM 8
#define NN (NPART * NPART) /* 4194304 ordered pairs per batch */

#define MJCHUNK 128   // median j-tile: 4.6 KB stage + 32 KB hist -> 4 blocks/CU

constexpr float LR = 0.1f;
constexpr float ALPHA = 0.9f;
constexpr float EPS = 1e-8f;
constexpr float INV_N = 1.0f / (float)NPART;
constexpr float LOG2E = 1.44269504088896340736f;

typedef float v2f __attribute__((ext_vector_type(2)));
typedef float v4f __attribute__((ext_vector_type(4)));

// ---------------------------------------------------------------------------
// init: zero radix histograms + select state (RMSprop s is never pre-zeroed:
// the first svgd step computes s = (1-a)*phi^2 directly, not reading s).
// ---------------------------------------------------------------------------
__global__ __launch_bounds__(256) void init_ws_k(unsigned* __restrict__ hist,
                                                 unsigned* __restrict__ prefix,
                                                 unsigned* __restrict__ rank) {
    const int tid = blockIdx.x * 256 + threadIdx.x;
    if (tid < BATCH * 2 * 256) hist[tid] = 0u;
    if (tid < BATCH * 2) {
        prefix[tid] = 0u;
        rank[tid] = (unsigned)(NN / 2) + (unsigned)(tid & 1); // 2097152 / 2097153
    }
}

// ---------------------------------------------------------------------------
// SYMMETRIC radix-select histogram pass (round-11 proven, unchanged).
// ---------------------------------------------------------------------------
__global__ __launch_bounds__(256) void median_hist_k(const float* __restrict__ x,
                                                     unsigned* __restrict__ hist,
                                                     const unsigned* __restrict__ prefix,
                                                     int shift) {
    __shared__ __align__(16) v4f xs0[MJCHUNK]; // xj dims 0-3
    __shared__ __align__(16) v4f xs1[MJCHUNK]; // xj dims 4-7
    __shared__ float rs[MJCHUNK];              // |xj|^2
    __shared__ unsigned lh[256 * 32];          // 32 KB slot-privatized bins

    const int b = blockIdx.x;
    const int tid = threadIdx.x;
    const int lane = tid & 63;   // j-lane
    const int slot = tid & 31;
    const int trow = tid >> 6;   // 0..3
    const float* xb = x + (size_t)b * NPART * DDIM;

    const unsigned p0 = prefix[2 * b + 0];
    const unsigned p1 = prefix[2 * b + 1];
    const bool same = (p0 == p1);
    const unsigned mask = (shift == 24) ? 0u : (0xFFFFFFFFu << (shift + 8));

    const int nsel = same ? 1 : 2;
    for (int sel = 0; sel < nsel; ++sel) {
        const unsigned pref = sel ? p1 : p0;
        __syncthreads();
        for (int t = tid; t < 256 * 32; t += 256) lh[t] = 0u;

        for (int sp = 0; sp < 2; ++sp) {
            const int strip = sp ? (255 - (int)blockIdx.y) : (int)blockIdx.y;
            const int ibase = strip * 8 + trow * 2;
            v2f xi[2][4];
            float q[2];
#pragma unroll
            for (int rr = 0; rr < 2; ++rr) {
                const v4f t0 = ((const v4f*)(xb + (size_t)(ibase + rr) * DDIM))[0];
                const v4f t1 = ((const v4f*)(xb + (size_t)(ibase + rr) * DDIM))[1];
                xi[rr][0] = t0.xy; xi[rr][1] = t0.zw;
                xi[rr][2] = t1.xy; xi[rr][3] = t1.zw;
                q[rr] = t0.x * t0.x + t0.y * t0.y + t0.z * t0.z + t0.w * t0.w
                      + t1.x * t1.x + t1.y * t1.y + t1.z * t1.z + t1.w * t1.w;
            }
            const int c0 = (strip >> 4) * MJCHUNK; // first chunk touching strip
            for (int cbase = c0; cbase < NPART; cbase += MJCHUNK) {
                __syncthreads();
                for (int t = tid; t < MJCHUNK; t += 256) {
                    const v4f u0 = ((const v4f*)(xb + (size_t)(cbase + t) * DDIM))[0];
                    const v4f u1 = ((const v4f*)(xb + (size_t)(cbase + t) * DDIM))[1];
                    xs0[t] = u0;
                    xs1[t] = u1;
                    rs[t] = u0.x * u0.x + u0.y * u0.y + u0.z * u0.z + u0.w * u0.w
                          + u1.x * u1.x + u1.y * u1.y + u1.z * u1.z + u1.w * u1.w;
                }
                __syncthreads();
#pragma unroll
                for (int j = lane; j < MJCHUNK; j += 64) {
                    const int jg = cbase + j;
                    const v4f A = xs0[j];
                    const v4f B = xs1[j];
                    const float r = rs[j];
                    const v2f A0 = A.xy, A1 = A.zw, B0 = B.xy, B1 = B.zw;
#pragma unroll
                    for (int rr = 0; rr < 2; ++rr) {
                        v2f p = A0 * xi[rr][0];
                        p += A1 * xi[rr][1];
                        p += B0 * xi[rr][2];
                        p += B1 * xi[rr][3];
                        const float sq = fmaxf(fmaf(-2.0f, p.x + p.y, q[rr] + r), 0.0f);
                        const unsigned u = __float_as_uint(sq);
                        if (jg > ibase + rr && (u & mask) == pref)
                            atomicAdd(&lh[((u >> shift) & 255u) * 32 + slot], 2u);
                    }
                }
            }
        }
        __syncthreads();
        unsigned tot = 0;
#pragma unroll
        for (int sct = 0; sct < 32; ++sct) tot += lh[tid * 32 + ((sct + tid) & 31)];
        if (tot) {
            atomicAdd(&hist[b * 512 + sel * 256 + tid], tot);
            if (same) atomicAdd(&hist[b * 512 + 256 + tid], tot);
        }
    }
}

// ---------------------------------------------------------------------------
// scan (round-11 proven, unchanged): diagonal zeros added analytically.
// Final round (shift==8): hpar = { -log2e/h, 2/h }.
// ---------------------------------------------------------------------------
__global__ void median_scan_k(unsigned* __restrict__ hist,
                              unsigned* __restrict__ prefix,
                              unsigned* __restrict__ rank,
                              int shift,
                              float* __restrict__ hpar) {
    __shared__ unsigned selv[16];
    const int t = threadIdx.x;
    if (t < 16) {
        const unsigned r = rank[t];
        const unsigned pref = prefix[t];
        const unsigned* hb = hist + t * 256;
        unsigned cum = 0;
        int bin = 0;
        for (; bin < 256; ++bin) {
            unsigned c = hb[bin];
            if (bin == 0 && pref == 0u) c += (unsigned)NPART; // diagonal zeros
            if (cum + c >= r) break;
            cum += c;
        }
        if (bin > 255) bin = 255;
        const unsigned np = pref | ((unsigned)bin << shift);
        prefix[t] = np;
        rank[t] = r - cum;
        selv[t] = np;
    }
    __syncthreads();
    for (int q = t; q < 16 * 256; q += 64) hist[q] = 0u;
    if (shift == 8 && t < BATCH) {
        const float v1 = __uint_as_float(selv[2 * t + 0]);
        const float v2 = __uint_as_float(selv[2 * t + 1]);
        const float med = 0.5f * (sqrtf(v1) + sqrtf(v2));
        const float h = (med * med) / logf((float)NPART);
        hpar[2 * t + 0] = -LOG2E / h;
        hpar[2 * t + 1] = 2.0f / h;
    }
}

// ---------------------------------------------------------------------------
// rs seed for the first svgd step: rs[row] = nih2_b * |x0_row|^2.
// Must run AFTER the median (needs hpar). 16384 rows.
// ---------------------------------------------------------------------------
__global__ __launch_bounds__(256) void rs0_k(const float* __restrict__ x,
                                             const float* __restrict__ hpar,
                                             float* __restrict__ rs) {
    const int row = blockIdx.x * 256 + threadIdx.x;
    if (row < BATCH * NPART) {
        const int b = row >> 11;
        const float nih2 = hpar[2 * b + 0];
        const v4f t0 = ((const v4f*)(x + (size_t)row * DDIM))[0];
        const v4f t1 = ((const v4f*)(x + (size_t)row * DDIM))[1];
        rs[row] = nih2 * (t0.x * t0.x + t0.y * t0.y + t0.z * t0.z + t0.w * t0.w
                        + t1.x * t1.x + t1.y * t1.y + t1.z * t1.z + t1.w * t1.w);
    }
}

// ---------------------------------------------------------------------------
// one SVGD + RMSprop step, dot-expansion in exp2 domain — BARRIER-FREE main
// loop (round-13 best-measured configuration, byte-identical):
//   K = exp2(cdot2*<xi,xj> + q + rs_j), q = nih2*|xi|^2
//   S0 = sum_j K;  V_d = sum_j K*xj_d;  U_d = S0*xi_d - V_d
//   phi = (1/N) * ( S0*(obs_d - xi_d) + (1 + 2/h)*U_d )
// block 256 = 64 j-lanes x 4 trows x 4 rows = 16 rows; grid (BATCH, 128).
// Epilogue writes rs_out from the new x (8-lane shfl row reduction).
// first=1: RMSprop state treated as zero (not read).
// ---------------------------------------------------------------------------
__global__ __launch_bounds__(256, 4) void svgd_step_k(const float* __restrict__ x_in,
                                                      float* __restrict__ x_out,
                                                      float* __restrict__ s,
                                                      const float* __restrict__ hpar,
                                                      const float* __restrict__ obs,
                                                      const float* __restrict__ rs_in,
                                                      float* __restrict__ rs_out,
                                                      int first) {
    __shared__ float part[16][8][9]; // 4.6 KB partial combine

    const int b = blockIdx.x;
    const int tid = threadIdx.x;
    const int lane = tid & 63;  // j-lane
    const int trow = tid >> 6;  // 0..3
    const float* xb = x_in + (size_t)b * NPART * DDIM;
    const float* rb = rs_in + (size_t)b * NPART;

    const float nih2 = hpar[2 * b + 0];  // -log2e/h
    const float c2 = hpar[2 * b + 1];    //  2/h
    const float cdot2 = -2.0f * nih2;

    const int ibase = blockIdx.y * 16 + trow * 4;
    v2f xi[4][4];
    float q[4];
#pragma unroll
    for (int rr = 0; rr < 4; ++rr) {
        const v4f t0 = ((const v4f*)(xb + (size_t)(ibase + rr) * DDIM))[0];
        const v4f t1 = ((const v4f*)(xb + (size_t)(ibase + rr) * DDIM))[1];
        xi[rr][0] = t0.xy; xi[rr][1] = t0.zw;
        xi[rr][2] = t1.xy; xi[rr][3] = t1.zw;
        q[rr] = nih2 * (t0.x * t0.x + t0.y * t0.y + t0.z * t0.z + t0.w * t0.w
                      + t1.x * t1.x + t1.y * t1.y + t1.z * t1.z + t1.w * t1.w);
    }

    float S0[4] = {0, 0, 0, 0};
    v2f V[4][4];
#pragma unroll
    for (int rr = 0; rr < 4; ++rr)
#pragma unroll
        for (int k = 0; k < 4; ++k) V[rr][k] = (v2f){0, 0};

#pragma unroll 4
    for (int j = lane; j < NPART; j += 64) {
        const v4f A = ((const v4f*)(xb + (size_t)j * DDIM))[0];
        const v4f B = ((const v4f*)(xb + (size_t)j * DDIM))[1];
        const float r = rb[j];
        const v2f A0 = A.xy, A1 = A.zw, B0 = B.xy, B1 = B.zw;
#pragma unroll
        for (int rr = 0; rr < 4; ++rr) {
            v2f p = A0 * xi[rr][0];
            p += A1 * xi[rr][1];
            p += B0 * xi[rr][2];
            p += B1 * xi[rr][3];
            const float K = __builtin_amdgcn_exp2f(fmaf(cdot2, p.x + p.y, q[rr] + r));
            S0[rr] += K;
            const v2f K2 = {K, K};
            V[rr][0] += A0 * K2;
            V[rr][1] += A1 * K2;
            V[rr][2] += B0 * K2;
            V[rr][3] += B1 * K2;
        }
    }

    // in-register lane pre-reduce (64 -> 8 partial lanes), then LDS combine
#pragma unroll
    for (int rr = 0; rr < 4; ++rr) {
        float t0 = S0[rr];
        float t1 = V[rr][0].x, t2 = V[rr][0].y;
        float t3 = V[rr][1].x, t4 = V[rr][1].y;
        float t5 = V[rr][2].x, t6 = V[rr][2].y;
        float t7 = V[rr][3].x, t8 = V[rr][3].y;
        t0 += __shfl_xor(t0, 32); t0 += __shfl_xor(t0, 16); t0 += __shfl_xor(t0, 8);
        t1 += __shfl_xor(t1, 32); t1 += __shfl_xor(t1, 16); t1 += __shfl_xor(t1, 8);
        t2 += __shfl_xor(t2, 32); t2 += __shfl_xor(t2, 16); t2 += __shfl_xor(t2, 8);
        t3 += __shfl_xor(t3, 32); t3 += __shfl_xor(t3, 16); t3 += __shfl_xor(t3, 8);
        t4 += __shfl_xor(t4, 32); t4 += __shfl_xor(t4, 16); t4 += __shfl_xor(t4, 8);
        t5 += __shfl_xor(t5, 32); t5 += __shfl_xor(t5, 16); t5 += __shfl_xor(t5, 8);
        t6 += __shfl_xor(t6, 32); t6 += __shfl_xor(t6, 16); t6 += __shfl_xor(t6, 8);
        t7 += __shfl_xor(t7, 32); t7 += __shfl_xor(t7, 16); t7 += __shfl_xor(t7, 8);
        t8 += __shfl_xor(t8, 32); t8 += __shfl_xor(t8, 16); t8 += __shfl_xor(t8, 8);
        if (lane < 8) {
            const int row = trow * 4 + rr;
            part[row][lane][0] = t0;
            part[row][lane][1] = t1;
            part[row][lane][2] = t2;
            part[row][lane][3] = t3;
            part[row][lane][4] = t4;
            part[row][lane][5] = t5;
            part[row][lane][6] = t6;
            part[row][lane][7] = t7;
            part[row][lane][8] = t8;
        }
    }
    __syncthreads();

    // phase 2: threads 0..127 = 16 rows x 8 dims; reduce 8 lane-partials
    if (tid < 128) {
        const int d2i = tid & 7;
        const int r2 = tid >> 3;
        const int i2 = blockIdx.y * 16 + r2;
        float S0t = 0.0f, Vt = 0.0f;
#pragma unroll
        for (int l = 0; l < 8; ++l) {
            S0t += part[r2][l][0];
            Vt += part[r2][l][1 + d2i];
        }
        const size_t idx = ((size_t)b * NPART + i2) * DDIM + d2i;
        const float xid = x_in[idx];
        const float obsd = obs[b * DDIM + d2i];
        const float U = fmaf(S0t, xid, -Vt);       // sum_j K*(xi - xj)
        const float T = fmaf(S0t, obsd - xid, U);  // sum_j K*(obs - xj)
        const float phi = INV_N * fmaf(c2, U, T);
        float sv;
        if (first) {
            sv = (1.0f - ALPHA) * phi * phi;
        } else {
            sv = ALPHA * s[idx] + (1.0f - ALPHA) * phi * phi;
        }
        s[idx] = sv;
        const float xn = xid + LR * phi / (sqrtf(sv) + EPS);
        x_out[idx] = xn;
        // rs for the NEXT step: row-sum of xn^2 over the 8 dims (8-lane group)
        float sq = xn * xn;
        sq += __shfl_xor(sq, 1);
        sq += __shfl_xor(sq, 2);
        sq += __shfl_xor(sq, 4);
        if (d2i == 0) rs_out[(size_t)b * NPART + i2] = nih2 * sq;
    }
}

// ---------------------------------------------------------------------------
extern "C" void kernel_launch(void* const* d_in, const int* in_sizes, int n_in,
                              void* d_out, int out_size, void* d_ws, size_t ws_size,
                              hipStream_t stream) {
    const float* x0 = (const float*)d_in[0];   // [8,2048,8]
    const float* obs = (const float*)d_in[1];  // [8,8]
    float* out = (float*)d_out;                // [8,2048,8]

    // workspace layout (~1.2 MB)
    float* xa = (float*)d_ws;                          // ping-pong x
    float* s = xa + BATCH * NPART * DDIM;              // RMSprop state
    unsigned* hist = (unsigned*)(s + BATCH * NPART * DDIM);
    unsigned* prefix = hist + BATCH * 2 * 256;
    unsigned* rank = prefix + BATCH * 2;
    float* hpar = (float*)(rank + BATCH * 2);
    float* rsA = hpar + BATCH * 2;                     // 64 KB
    float* rsB = rsA + BATCH * NPART;                  // 64 KB

    init_ws_k<<<16, 256, 0, stream>>>(hist, prefix, rank);

    // median via 3-round SYMMETRIC radix select on float bit patterns
    for (int r = 0; r < 3; ++r) {
        const int shift = 24 - 8 * r;
        median_hist_k<<<dim3(BATCH, 128), 256, 0, stream>>>(x0, hist, prefix, shift);
        median_scan_k<<<1, 64, 0, stream>>>(hist, prefix, rank, shift, hpar);
    }

    // seed rs from x0 (needs hpar -> after median)
    rs0_k<<<64, 256, 0, stream>>>(x0, hpar, rsA);

    // 5 SVGD iterations, ping-ponging x between d_out and ws and rs A<->B
    svgd_step_k<<<dim3(BATCH, 128), 256, 0, stream>>>(x0, out, s, hpar, obs, rsA, rsB, 1);
    svgd_step_k<<<dim3(BATCH, 128), 256, 0, stream>>>(out, xa, s, hpar, obs, rsB, rsA, 0);
    svgd_step_k<<<dim3(BATCH, 128), 256, 0, stream>>>(xa, out, s, hpar, obs, rsA, rsB, 0);
    svgd_step_k<<<dim3(BATCH, 128), 256, 0, stream>>>(out, xa, s, hpar, obs, rsB, rsA, 0);
    svgd_step_k<<<dim3(BATCH, 128), 256, 0, stream>>>(xa, out, s, hpar, obs, rsA, rsB, 0);
}